// Round 1
// baseline (1147.121 us; speedup 1.0000x reference)
//
#include <hip/hip_runtime.h>

typedef _Float16 half8 __attribute__((ext_vector_type(8)));
typedef _Float16 half4h __attribute__((ext_vector_type(4)));
typedef float f32x4 __attribute__((ext_vector_type(4)));

#define DIM 256
#define BK 32
#define MT 64
#define XS_STRIDE 40     // 32 f16 + 8 pad -> 80B rows, breaks pow2 bank stride
#define HS_STRIDE 264    // 256 f16 + 8 pad
#define NSEG 4096

// ---------------- prep: W1t[n*256+k] = (f16)W1[k*256+n], same for W2 ----------------
__global__ void prep_weights(const float* __restrict__ W1, const float* __restrict__ W2,
                             _Float16* __restrict__ W1t, _Float16* __restrict__ W2t) {
    int e = blockIdx.x * 256 + threadIdx.x;   // 512 blocks * 256 = 131072 = 2*65536
    const float* src = W1;
    _Float16* dst = W1t;
    if (e >= 65536) { src = W2; dst = W2t; e -= 65536; }
    int n = e >> 8, k = e & 255;
    dst[n * DIM + k] = (_Float16)src[k * DIM + n];
}

// ---------------- fused: s = silu(x@W1+b1)@W2+b2 ; e = exp(s) ;
//                  scatter-accumulate num += e*x, den += e per (segment, feature) ----
__global__ __launch_bounds__(256, 2)
void fused_mlp_scatter(const float* __restrict__ x, const int* __restrict__ index,
                       const _Float16* __restrict__ W1t, const float* __restrict__ b1,
                       const _Float16* __restrict__ W2t, const float* __restrict__ b2,
                       float* __restrict__ gnum, float* __restrict__ gden)
{
    __shared__ __align__(16) char smem[59648];
    _Float16* xs   = (_Float16*)smem;            // [64][40]  f16   (5120 B)
    _Float16* wsld = (_Float16*)(smem + 5120);   // [256][40] f16   (20480 B)
    _Float16* hs   = (_Float16*)(smem + 25600);  // [64][264] f16   (33792 B)
    int*      segl = (int*)(smem + 59392);       // [64] int
    float*    epi  = (float*)smem;               // epilogue reuse: num[8][256], den[8][256]

    const int tid  = threadIdx.x;
    const int wave = tid >> 6;
    const int lane = tid & 63;
    const int q    = lane >> 4;
    const int l15  = lane & 15;
    const int row0 = blockIdx.x * MT;

    if (tid < 64) segl[tid] = index[row0 + tid];

    const f32x4 zf = {0.f, 0.f, 0.f, 0.f};
    f32x4 acc[4][4];
#pragma unroll
    for (int i = 0; i < 4; ++i)
#pragma unroll
        for (int j = 0; j < 4; ++j) acc[i][j] = zf;

    const int xr = tid >> 2;
    const int xc = (tid & 3) * 8;

    // ---- phase 1: h = silu(x @ W1 + b1), full 64x256 tile ----
#pragma unroll 1
    for (int kk = 0; kk < 8; ++kk) {
        __syncthreads();
        {   // stage x tile 64x32 fp32 -> f16
            const float* src = x + (size_t)(row0 + xr) * DIM + kk * BK + xc;
            f32x4 v0 = *(const f32x4*)src;
            f32x4 v1 = *(const f32x4*)(src + 4);
            half4h h0, h1;
#pragma unroll
            for (int c = 0; c < 4; ++c) { h0[c] = (_Float16)v0[c]; h1[c] = (_Float16)v1[c]; }
            *(half4h*)(xs + xr * XS_STRIDE + xc) = h0;
            *(half4h*)(xs + xr * XS_STRIDE + xc + 4) = h1;
        }
#pragma unroll
        for (int p = 0; p < 4; ++p) {   // stage W1t tile 256x32 f16
            int ci = tid + p * 256;
            int n = ci >> 2, c = (ci & 3) * 8;
            *(half8*)(wsld + n * XS_STRIDE + c) = *(const half8*)(W1t + n * DIM + kk * BK + c);
        }
        __syncthreads();
        half8 af[4], bf[4];
#pragma unroll
        for (int i = 0; i < 4; ++i)
            af[i] = *(const half8*)(xs + (i * 16 + l15) * XS_STRIDE + q * 8);
#pragma unroll
        for (int j = 0; j < 4; ++j)
            bf[j] = *(const half8*)(wsld + (wave * 64 + j * 16 + l15) * XS_STRIDE + q * 8);
#pragma unroll
        for (int i = 0; i < 4; ++i)
#pragma unroll
            for (int j = 0; j < 4; ++j)
                acc[i][j] = __builtin_amdgcn_mfma_f32_16x16x32_f16(af[i], bf[j], acc[i][j], 0, 0, 0);
    }

    {   // bias + silu -> hs (f16)
        float b1v[4];
#pragma unroll
        for (int j = 0; j < 4; ++j) b1v[j] = b1[wave * 64 + j * 16 + l15];
#pragma unroll
        for (int i = 0; i < 4; ++i)
#pragma unroll
            for (int j = 0; j < 4; ++j)
#pragma unroll
                for (int r = 0; r < 4; ++r) {
                    float v = acc[i][j][r] + b1v[j];
                    float sg = 1.f / (1.f + __expf(-v));
                    hs[(i * 16 + q * 4 + r) * HS_STRIDE + wave * 64 + j * 16 + l15] = (_Float16)(v * sg);
                }
    }

    // ---- phase 2: s = h @ W2 + b2 ----
#pragma unroll
    for (int i = 0; i < 4; ++i)
#pragma unroll
        for (int j = 0; j < 4; ++j) acc[i][j] = zf;

#pragma unroll 1
    for (int kk = 0; kk < 8; ++kk) {
        __syncthreads();   // covers hs writes (first iter) and prior frag reads of wsld
#pragma unroll
        for (int p = 0; p < 4; ++p) {
            int ci = tid + p * 256;
            int n = ci >> 2, c = (ci & 3) * 8;
            *(half8*)(wsld + n * XS_STRIDE + c) = *(const half8*)(W2t + n * DIM + kk * BK + c);
        }
        __syncthreads();
        half8 af[4], bf[4];
#pragma unroll
        for (int i = 0; i < 4; ++i)
            af[i] = *(const half8*)(hs + (i * 16 + l15) * HS_STRIDE + kk * BK + q * 8);
#pragma unroll
        for (int j = 0; j < 4; ++j)
            bf[j] = *(const half8*)(wsld + (wave * 64 + j * 16 + l15) * XS_STRIDE + q * 8);
#pragma unroll
        for (int i = 0; i < 4; ++i)
#pragma unroll
            for (int j = 0; j < 4; ++j)
                acc[i][j] = __builtin_amdgcn_mfma_f32_16x16x32_f16(af[i], bf[j], acc[i][j], 0, 0, 0);
    }

    __syncthreads();   // all frag reads done; region A (xs/wsld) reusable

    const int seg0 = segl[0];
    const int nseg = segl[63] - seg0 + 1;   // index sorted
    float b2v[4];
#pragma unroll
    for (int j = 0; j < 4; ++j) b2v[j] = b2[wave * 64 + j * 16 + l15];

    if (nseg <= 8) {
        float* enum_ = epi;          // [8][256]
        float* eden  = epi + 2048;   // [8][256]
        for (int t = tid; t < 2048; t += 256) { enum_[t] = 0.f; eden[t] = 0.f; }
        __syncthreads();
#pragma unroll
        for (int i = 0; i < 4; ++i)
#pragma unroll
            for (int j = 0; j < 4; ++j)
#pragma unroll
                for (int r = 0; r < 4; ++r) {
                    int rl  = i * 16 + q * 4 + r;
                    int col = wave * 64 + j * 16 + l15;
                    float e = __expf(acc[i][j][r] + b2v[j]);   // |s|<~4 with this data: no max needed
                    float xv = x[(size_t)(row0 + rl) * DIM + col];
                    int sl = segl[rl] - seg0;
                    atomicAdd(&enum_[sl * 256 + col], e * xv);
                    atomicAdd(&eden[sl * 256 + col], e);
                }
        __syncthreads();
        for (int sl = 0; sl < nseg; ++sl) {
            atomicAdd(&gnum[(size_t)(seg0 + sl) * DIM + tid], enum_[sl * 256 + tid]);
            atomicAdd(&gden[(size_t)(seg0 + sl) * DIM + tid], eden[sl * 256 + tid]);
        }
    } else {
        // generic fallback: direct global atomics (rare: >8 segments in 64 rows)
#pragma unroll
        for (int i = 0; i < 4; ++i)
#pragma unroll
            for (int j = 0; j < 4; ++j)
#pragma unroll
                for (int r = 0; r < 4; ++r) {
                    int rl  = i * 16 + q * 4 + r;
                    int col = wave * 64 + j * 16 + l15;
                    float e = __expf(acc[i][j][r] + b2v[j]);
                    float xv = x[(size_t)(row0 + rl) * DIM + col];
                    int sg = segl[rl];
                    atomicAdd(&gnum[(size_t)sg * DIM + col], e * xv);
                    atomicAdd(&gden[(size_t)sg * DIM + col], e);
                }
    }
}

// ---------------- normalize: sx = num / den (0 for empty segments) ----------------
__global__ void normalize_sx(const float* __restrict__ num, const float* __restrict__ den,
                             float* __restrict__ sx) {
    int i = blockIdx.x * 256 + threadIdx.x;   // 4096 blocks -> exactly NSEG*DIM
    float d = den[i];
    sx[i] = (d > 0.f) ? num[i] / d : 0.f;
}

// ---------------- readout1: h2 = silu(sx @ W3 + b3), [4096,256] ----------------
__global__ __launch_bounds__(256)
void readout1(const float* __restrict__ sx, const float* __restrict__ W3,
              const float* __restrict__ b3, float* __restrict__ h2) {
    __shared__ float sxl[16 * 256];
    const int tid = threadIdx.x;
    const int row0 = blockIdx.x * 16;
#pragma unroll
    for (int p = 0; p < 4; ++p) {
        int fi = tid + p * 256;
        int r = fi >> 6, c = (fi & 63) * 4;
        *(f32x4*)(sxl + r * 256 + c) = *(const f32x4*)(sx + (size_t)(row0 + r) * 256 + c);
    }
    __syncthreads();
    const int c0 = (tid & 63) * 4;
    const int rg = tid >> 6;         // 4 row-groups of 4 rows
    f32x4 bv = *(const f32x4*)(b3 + c0);
    float acc[4][4];
#pragma unroll
    for (int r = 0; r < 4; ++r)
#pragma unroll
        for (int c = 0; c < 4; ++c) acc[r][c] = bv[c];
    for (int k = 0; k < 256; ++k) {
        f32x4 w = *(const f32x4*)(W3 + (size_t)k * 256 + c0);
#pragma unroll
        for (int r = 0; r < 4; ++r) {
            float s = sxl[(rg * 4 + r) * 256 + k];
#pragma unroll
            for (int c = 0; c < 4; ++c) acc[r][c] += s * w[c];
        }
    }
#pragma unroll
    for (int r = 0; r < 4; ++r) {
        f32x4 o;
#pragma unroll
        for (int c = 0; c < 4; ++c) {
            float v = acc[r][c];
            o[c] = v / (1.f + __expf(-v));
        }
        *(f32x4*)(h2 + (size_t)(row0 + rg * 4 + r) * 256 + c0) = o;
    }
}

// ---------------- readout2: out = h2 @ W4 + b4, [4096,128] ----------------
__global__ __launch_bounds__(256)
void readout2(const float* __restrict__ h2, const float* __restrict__ W4,
              const float* __restrict__ b4, float* __restrict__ out) {
    __shared__ float hl[16 * 256];
    const int tid = threadIdx.x;
    const int row0 = blockIdx.x * 16;
#pragma unroll
    for (int p = 0; p < 4; ++p) {
        int fi = tid + p * 256;
        int r = fi >> 6, c = (fi & 63) * 4;
        *(f32x4*)(hl + r * 256 + c) = *(const f32x4*)(h2 + (size_t)(row0 + r) * 256 + c);
    }
    __syncthreads();
    const int c0 = (tid & 31) * 4;   // 128 cols / 4
    const int rg = tid >> 5;         // 8 row-groups of 2 rows
    f32x4 bv = *(const f32x4*)(b4 + c0);
    float acc[2][4];
#pragma unroll
    for (int r = 0; r < 2; ++r)
#pragma unroll
        for (int c = 0; c < 4; ++c) acc[r][c] = bv[c];
    for (int k = 0; k < 256; ++k) {
        f32x4 w = *(const f32x4*)(W4 + (size_t)k * 128 + c0);
#pragma unroll
        for (int r = 0; r < 2; ++r) {
            float s = hl[(rg * 2 + r) * 256 + k];
#pragma unroll
            for (int c = 0; c < 4; ++c) acc[r][c] += s * w[c];
        }
    }
#pragma unroll
    for (int r = 0; r < 2; ++r) {
        f32x4 o;
#pragma unroll
        for (int c = 0; c < 4; ++c) o[c] = acc[r][c];
        *(f32x4*)(out + (size_t)(row0 + rg * 2 + r) * 128 + c0) = o;
    }
}

extern "C" void kernel_launch(void* const* d_in, const int* in_sizes, int n_in,
                              void* d_out, int out_size, void* d_ws, size_t ws_size,
                              hipStream_t stream) {
    const float* x   = (const float*)d_in[0];
    const int*   idx = (const int*)d_in[1];
    const float* W1  = (const float*)d_in[2];
    const float* b1  = (const float*)d_in[3];
    const float* W2  = (const float*)d_in[4];
    const float* b2  = (const float*)d_in[5];
    const float* W3  = (const float*)d_in[6];
    const float* b3  = (const float*)d_in[7];
    const float* W4  = (const float*)d_in[8];
    const float* b4  = (const float*)d_in[9];
    float* out = (float*)d_out;
    char* ws = (char*)d_ws;

    _Float16* W1t = (_Float16*)ws;                          // 131072 B
    _Float16* W2t = (_Float16*)(ws + 131072);               // 131072 B
    float* gnum = (float*)(ws + 262144);                    // 4 MB
    float* gden = (float*)(ws + 262144 + 4194304);          // 4 MB
    float* sx   = (float*)(ws + 262144 + 8388608);          // 4 MB
    float* h2   = (float*)(ws + 262144 + 12582912);         // 4 MB

    hipMemsetAsync(ws + 262144, 0, 8388608, stream);        // zero num/den every launch

    prep_weights<<<512, 256, 0, stream>>>(W1, W2, W1t, W2t);
    fused_mlp_scatter<<<4096, 256, 0, stream>>>(x, idx, W1t, b1, W2t, b2, gnum, gden);
    normalize_sx<<<4096, 256, 0, stream>>>(gnum, gden, sx);
    readout1<<<256, 256, 0, stream>>>(sx, W3, b3, h2);
    readout2<<<256, 256, 0, stream>>>(h2, W4, b4, out);
}